// Round 7
// baseline (558.628 us; speedup 1.0000x reference)
//
#include <hip/hip_runtime.h>

// Problem constants
#define B_N 4096
#define T_N 512
// Output layout (floats): final (B,T,2) | fwd_out (B,2) | noise (B,T,1)
#define FWD_OFF   (B_N * T_N * 2)        // 4194304
#define NOISE_OFF (FWD_OFF + B_N * 2)    // 4202496

#define S_SIG  (-1.4426950408889634f)   // -log2(e)
#define S_TANH (-2.8853900817779268f)   // -2*log2(e)

__device__ __forceinline__ float sig_acc(float a) {
    return __builtin_amdgcn_rcpf(1.0f + __builtin_amdgcn_exp2f(a));
}
__device__ __forceinline__ float tanh_acc(float a) {
    return fmaf(2.0f, __builtin_amdgcn_rcpf(1.0f + __builtin_amdgcn_exp2f(a)), -1.0f);
}
__device__ __forceinline__ float tanh_nat(float v) { return tanh_acc(v * S_TANH); }
__device__ __forceinline__ float act_ab(float a, float A, float Bc) {
    float r = __builtin_amdgcn_rcpf(1.0f + __builtin_amdgcn_exp2f(a));
    return fmaf(A, r, Bc);
}
// ds_bpermute with a precomputed (loop-invariant) byte address
__device__ __forceinline__ float bperm(int byteaddr, float v) {
    return __int_as_float(__builtin_amdgcn_ds_bpermute(byteaddr, __float_as_int(v)));
}

// 32 lanes per batch element. Grid = 4096*32 = 131072 threads = 2048 waves
// = exactly 2 waves/SIMD. waves_per_eu(2,2) tells the allocator to plan for
// exactly 2 waves/EU (256-VGPR budget) so the ~108 live floats stay resident
// (R4 without this: allocator targeted 8 waves -> 64 VGPR -> reload storm).
__global__ __launch_bounds__(256) __attribute__((amdgpu_waves_per_eu(2, 2)))
void fused_kernel(
    const float* __restrict__ x,
    const float* __restrict__ eWih0, const float* __restrict__ eWhh0,
    const float* __restrict__ ebih0, const float* __restrict__ ebhh0,
    const float* __restrict__ eWih1, const float* __restrict__ eWhh1,
    const float* __restrict__ ebih1, const float* __restrict__ ebhh1,
    const float* __restrict__ dWih0, const float* __restrict__ dWhh0,
    const float* __restrict__ dbih0, const float* __restrict__ dbhh0,
    const float* __restrict__ dWih1, const float* __restrict__ dWhh1,
    const float* __restrict__ dbih1, const float* __restrict__ dbhh1,
    const float* __restrict__ fcW, const float* __restrict__ fcb,
    const float* __restrict__ outW, const float* __restrict__ outb,
    float* __restrict__ out)
{
    const int tid    = blockIdx.x * 256 + threadIdx.x;
    const int b      = tid >> 5;          // batch element
    const int lane32 = tid & 31;          // lane within the element's 32-group
    const int wl     = threadIdx.x & 63;  // lane within the wave

    // =================== ENCODER (gate-row-parallel, H=4) ===================
    // 16-lane groups; the two halves of a 32-group duplicate the work, which
    // leaves identical state in both halves for the decoder handoff.
    const int r16 = lane32 & 15;
    const int u4  = r16 & 3;
    const int kk  = r16 >> 2;
    const float sc = (kk == 2) ? S_TANH : S_SIG;
    const float Ak = (kk == 2) ? 2.0f : 1.0f;
    const float Bk = (kk == 2) ? -1.0f : 0.0f;

    // Loop-invariant bpermute byte addresses (16-wide groups)
    const int base16b = (wl & ~15) << 2;
    const int eb_f = base16b + ((u4 + 4) << 2);
    const int eb_g = base16b + ((u4 + 8) << 2);
    const int eb_o = base16b + ((u4 + 12) << 2);

    float h0v[4] = {0.f, 0.f, 0.f, 0.f};
    float h1v[4] = {0.f, 0.f, 0.f, 0.f};
    float c0 = 0.f, c1 = 0.f;
    float fw0, fw1;

    {
        float ew0  = eWih0[r16] * sc;
        float eb0c = (ebih0[r16] + ebhh0[r16]) * sc;
        float eb1c = (ebih1[r16] + ebhh1[r16]) * sc;
        float ewh0[4], ewi1[4], ewh1[4];
#pragma unroll
        for (int j = 0; j < 4; ++j) {
            ewh0[j] = eWhh0[r16 * 4 + j] * sc;
            ewi1[j] = eWih1[r16 * 4 + j] * sc;
            ewh1[j] = eWhh1[r16 * 4 + j] * sc;
        }

        const float4* __restrict__ xq4 = (const float4*)(x + (long)b * T_N);
        float4 xq = xq4[0];

        auto estep = [&](float xc) {
            // L1 partial from previous h1 (independent of L0 chain)
            float p = eb1c;
#pragma unroll
            for (int j = 0; j < 4; ++j) p = fmaf(ewh1[j], h1v[j], p);

            float g = fmaf(ew0, xc, eb0c);
#pragma unroll
            for (int j = 0; j < 4; ++j) g = fmaf(ewh0[j], h0v[j], g);
            float gate = act_ab(g, Ak, Bk);
            float fv = bperm(eb_f, gate);
            float gv = bperm(eb_g, gate);
            float ov = bperm(eb_o, gate);
            c0 = fmaf(fv, c0, gate * gv);      // valid on kk==0 lanes
            float h0u = ov * tanh_nat(c0);
#pragma unroll
            for (int j = 0; j < 4; ++j) h0v[j] = bperm(base16b + (j << 2), h0u);

            float q = ewi1[0] * h0v[0];
#pragma unroll
            for (int j = 1; j < 4; ++j) q = fmaf(ewi1[j], h0v[j], q);
            float gate1 = act_ab(p + q, Ak, Bk);
            fv = bperm(eb_f, gate1);
            gv = bperm(eb_g, gate1);
            ov = bperm(eb_o, gate1);
            c1 = fmaf(fv, c1, gate1 * gv);
            float h1u = ov * tanh_nat(c1);
#pragma unroll
            for (int j = 0; j < 4; ++j) h1v[j] = bperm(base16b + (j << 2), h1u);
        };

        for (int tb = 0; tb < T_N / 4; ++tb) {
            float4 xn = (tb + 1 < T_N / 4) ? xq4[tb + 1] : xq;  // prefetch
            estep(xq.x); estep(xq.y); estep(xq.z); estep(xq.w);
            xq = xn;
        }

        fw0 = fcb[0]; fw1 = fcb[1];
#pragma unroll
        for (int j = 0; j < 4; ++j) {
            fw0 = fmaf(fcW[j], h1v[j], fw0);
            fw1 = fmaf(fcW[4 + j], h1v[j], fw1);
        }
        if (lane32 == 0) {
            out[FWD_OFF + b * 2 + 0] = fw0;
            out[FWD_OFF + b * 2 + 1] = fw1;
        }
    }

    // =================== DECODER: gate-pair split (H=10, 32 lanes) ===================
    // lane = (u, s): u = lane32&15 (units 0..9 live, 10..15 shadow), s = lane32>>4.
    // s=0 owns rows {i (k=0), g (k=2)}; s=1 owns {f (k=1), o (k=3)}.
    // c-state lives on s=1 lanes; i*tanh(g) is local on s=0, one bpermute moves it.
    const int u  = r16;
    const int uc = (u < 10) ? u : 9;
    const int s  = lane32 >> 4;

    const int rowA = s * 10 + uc;        // i (s=0) or f (s=1): sigmoid
    const int rowB = (2 + s) * 10 + uc;  // g (s=0) or o (s=1)
    const float scB = s ? S_SIG : S_TANH;
    const float A1  = s ? 1.0f : 2.0f;
    const float B1  = s ? 0.0f : -1.0f;

    float wih0A = dWih0[rowA] * S_SIG;
    float wih0B = dWih0[rowB] * scB;
    float b0A = (dbih0[rowA] + dbhh0[rowA]) * S_SIG;
    float b0B = (dbih0[rowB] + dbhh0[rowB]) * scB;
    float b1A = (dbih1[rowA] + dbhh1[rowA]) * S_SIG;
    float b1B = (dbih1[rowB] + dbhh1[rowB]) * scB;
    float whh0A[10], whh0B[10], wih1A[10], wih1B[10], whh1A[10], whh1B[10];
#pragma unroll
    for (int j = 0; j < 10; ++j) {
        whh0A[j] = dWhh0[rowA * 10 + j] * S_SIG;
        whh0B[j] = dWhh0[rowB * 10 + j] * scB;
        wih1A[j] = dWih1[rowA * 10 + j] * S_SIG;
        wih1B[j] = dWih1[rowB * 10 + j] * scB;
        whh1A[j] = dWhh1[rowA * 10 + j] * S_SIG;
        whh1B[j] = dWhh1[rowB * 10 + j] * scB;
    }
    float outw[10];
#pragma unroll
    for (int j = 0; j < 10; ++j) outw[j] = outW[j];
    const float outb0 = outb[0];

    // Loop-invariant bpermute byte addresses (32-wide groups)
    const int grpb  = (wl & ~31) << 2;
    const int bp_ig = grpb + (u << 2);          // lane (u, s=0)
    int bp_h[10];
#pragma unroll
    for (int j = 0; j < 10; ++j) bp_h[j] = grpb + ((16 + j) << 2);  // lane (j, s=1)

    // Handoff: c-state valid on kk==0 lanes (lane32 = u4 and 16+u4); pull to all.
    float t0 = bperm(grpb + (u << 2), c0);
    float t1 = bperm(grpb + (u << 2), c1);
    float dc0 = (u < 4) ? t0 : 0.f;
    float dc1 = (u < 4) ? t1 : 0.f;

    float dh0[10], dh1[10];
#pragma unroll
    for (int j = 0; j < 10; ++j) {
        dh0[j] = (j < 4) ? h0v[j] : 0.f;
        dh1[j] = (j < 4) ? h1v[j] : 0.f;
    }

    float* __restrict__ noise_base = out + NOISE_OFF + b * T_N;
    float2* __restrict__ fin_base  = (float2*)out + b * T_N;

    float my_noise = 0.f;

    for (int t = 0; t < T_N; ++t) {
        const float inp = dh1[0];

        // L1 partial from previous h1 (independent of L0 chain); split chains
        float pA0 = b1A, pA1 = 0.f, pB0 = b1B, pB1 = 0.f;
#pragma unroll
        for (int j = 0; j < 10; j += 2) {
            pA0 = fmaf(whh1A[j], dh1[j], pA0);
            pA1 = fmaf(whh1A[j + 1], dh1[j + 1], pA1);
            pB0 = fmaf(whh1B[j], dh1[j], pB0);
            pB1 = fmaf(whh1B[j + 1], dh1[j + 1], pB1);
        }
        const float pA = pA0 + pA1, pB = pB0 + pB1;

        // L0 gate rows; split chains
        float aA0 = fmaf(wih0A, inp, b0A), aA1 = 0.f;
        float aB0 = fmaf(wih0B, inp, b0B), aB1 = 0.f;
#pragma unroll
        for (int j = 0; j < 10; j += 2) {
            aA0 = fmaf(whh0A[j], dh0[j], aA0);
            aA1 = fmaf(whh0A[j + 1], dh0[j + 1], aA1);
            aB0 = fmaf(whh0B[j], dh0[j], aB0);
            aB1 = fmaf(whh0B[j + 1], dh0[j + 1], aB1);
        }
        float gateA = sig_acc(aA0 + aA1);        // i (s=0) / f (s=1)
        float gateB = act_ab(aB0 + aB1, A1, B1); // tanh(g) (s=0) / o (s=1)
        float ig  = gateA * gateB;               // i*tanh(g) on s=0
        float igx = bperm(bp_ig, ig);
        dc0 = fmaf(gateA, dc0, igx);             // s=1: f*c0 + i*g
        float h0u = gateB * tanh_nat(dc0);       // s=1: o * tanh(c0)
#pragma unroll
        for (int j = 0; j < 10; ++j) dh0[j] = bperm(bp_h[j], h0u);

        // L1 gate rows (post-broadcast half); split chains
        float qA0 = 0.f, qA1 = 0.f, qB0 = 0.f, qB1 = 0.f;
#pragma unroll
        for (int j = 0; j < 10; j += 2) {
            qA0 = fmaf(wih1A[j], dh0[j], qA0);
            qA1 = fmaf(wih1A[j + 1], dh0[j + 1], qA1);
            qB0 = fmaf(wih1B[j], dh0[j], qB0);
            qB1 = fmaf(wih1B[j + 1], dh0[j + 1], qB1);
        }
        gateA = sig_acc(pA + qA0 + qA1);
        gateB = act_ab(pB + qB0 + qB1, A1, B1);
        ig  = gateA * gateB;
        igx = bperm(bp_ig, ig);
        dc1 = fmaf(gateA, dc1, igx);
        float h1u = gateB * tanh_nat(dc1);
#pragma unroll
        for (int j = 0; j < 10; ++j) dh1[j] = bperm(bp_h[j], h1u);

        // noise_t = dec_out . out_W + out_b (uniform on all 32 lanes)
        float nz = outb0;
#pragma unroll
        for (int j = 0; j < 10; ++j) nz = fmaf(outw[j], dh1[j], nz);

        // lane keeps t with t%32==lane32; flush coalesced every 32 steps
        my_noise = ((t & 31) == lane32) ? nz : my_noise;
        if ((t & 31) == 31) {
            const int off = (t - 31) + lane32;
            noise_base[off] = my_noise;
            float2 fin;
            fin.x = my_noise + fw0;
            fin.y = my_noise + fw1;
            fin_base[off] = fin;
        }
    }
}

extern "C" void kernel_launch(void* const* d_in, const int* in_sizes, int n_in,
                              void* d_out, int out_size, void* d_ws, size_t ws_size,
                              hipStream_t stream) {
    const float* x     = (const float*)d_in[0];
    // d_in[1] = context (unused by the reference)
    const float* eWih0 = (const float*)d_in[2];
    const float* eWhh0 = (const float*)d_in[3];
    const float* ebih0 = (const float*)d_in[4];
    const float* ebhh0 = (const float*)d_in[5];
    const float* eWih1 = (const float*)d_in[6];
    const float* eWhh1 = (const float*)d_in[7];
    const float* ebih1 = (const float*)d_in[8];
    const float* ebhh1 = (const float*)d_in[9];
    const float* dWih0 = (const float*)d_in[10];
    const float* dWhh0 = (const float*)d_in[11];
    const float* dbih0 = (const float*)d_in[12];
    const float* dbhh0 = (const float*)d_in[13];
    const float* dWih1 = (const float*)d_in[14];
    const float* dWhh1 = (const float*)d_in[15];
    const float* dbih1 = (const float*)d_in[16];
    const float* dbhh1 = (const float*)d_in[17];
    const float* fcW   = (const float*)d_in[18];
    const float* fcb   = (const float*)d_in[19];
    const float* outW  = (const float*)d_in[20];
    const float* outb  = (const float*)d_in[21];

    float* out = (float*)d_out;

    // 4096 elems x 32 lanes = 131072 threads = 2048 waves = 2 waves/SIMD
    fused_kernel<<<dim3((B_N * 32) / 256), dim3(256), 0, stream>>>(
        x, eWih0, eWhh0, ebih0, ebhh0, eWih1, eWhh1, ebih1, ebhh1,
        dWih0, dWhh0, dbih0, dbhh0, dWih1, dWhh1, dbih1, dbhh1,
        fcW, fcb, outW, outb, out);
}